// Round 1
// baseline (500.541 us; speedup 1.0000x reference)
//
#include <hip/hip_runtime.h>

#define SEQ   2048
#define NHEAD 16
#define HD    64
#define HID   1024
#define NQKV  1152
#define MROWS 4096  // B*S

typedef unsigned short u16;
typedef __attribute__((ext_vector_type(8))) __bf16 bfrag;
typedef __attribute__((ext_vector_type(4))) float f32x4;
typedef __attribute__((ext_vector_type(4))) short s16x4;

__device__ __forceinline__ u16 f2bf(float f) {
  unsigned u = __float_as_uint(f);
  u += 0x7fffu + ((u >> 16) & 1u);
  return (u16)(u >> 16);
}

// ---------- converts ----------
__global__ void k_cvt_x(const float* __restrict__ x, u16* __restrict__ o) {
  int i = (blockIdx.x * 256 + threadIdx.x) * 4;
  float4 v = *reinterpret_cast<const float4*>(x + i);
  s16x4 r;
  r.x = (short)f2bf(v.x); r.y = (short)f2bf(v.y);
  r.z = (short)f2bf(v.z); r.w = (short)f2bf(v.w);
  *reinterpret_cast<s16x4*>(o + i) = r;
}

// Wt[n][k] = W*[k][n] for concatenated q|k|v columns, bf16
__global__ void k_cvt_wqkv(const float* __restrict__ Wq, const float* __restrict__ Wk,
                           const float* __restrict__ Wv, u16* __restrict__ Wt) {
  int t = blockIdx.x * 256 + threadIdx.x;  // t < 1152*1024
  int n = t >> 10, k = t & 1023;
  float v;
  if (n < 1024)      v = Wq[k * 1024 + n];
  else if (n < 1088) v = Wk[k * 64 + (n - 1024)];
  else               v = Wv[k * 64 + (n - 1088)];
  Wt[t] = f2bf(v);
}

__global__ void k_cvt_wo(const float* __restrict__ Wo, u16* __restrict__ Wt) {
  int t = blockIdx.x * 256 + threadIdx.x;  // t < 1024*1024
  int n = t >> 10, k = t & 1023;
  Wt[t] = f2bf(Wo[k * 1024 + n]);
}

__global__ void k_bias(const float* __restrict__ bq, const float* __restrict__ bk,
                       const float* __restrict__ bv, float* __restrict__ bqkv) {
  int t = blockIdx.x * 256 + threadIdx.x;
  if (t >= NQKV) return;
  float v;
  if (t < 1024)      v = bq[t];
  else if (t < 1088) v = bk[t - 1024];
  else               v = bv[t - 1088];
  bqkv[t] = v;
}

// Vt[b][d][s] = V[b][s][d]  (V = QKV cols 1088..1151)
__global__ void k_vt(const u16* __restrict__ QKV, u16* __restrict__ Vt) {
  int t = blockIdx.x * 256 + threadIdx.x;  // t < 2*64*2048
  int s = t & 2047, d = (t >> 11) & 63, b = t >> 17;
  Vt[t] = QKV[(size_t)(b * SEQ + s) * NQKV + 1088 + d];
}

// ---------- GEMM: C[M][N] = A[M][K] * Bt[N][K]^T + bias ----------
template <int STORE_BF16>
__global__ __launch_bounds__(256) void k_gemm(const u16* __restrict__ A,
                                              const u16* __restrict__ Bt,
                                              const float* __restrict__ bias,
                                              void* __restrict__ Cout,
                                              int M, int N, int K) {
  __shared__ __align__(16) u16 Al[128 * 32];
  __shared__ __align__(16) u16 Bl[128 * 32];
  const int tid = threadIdx.x;
  const int lane = tid & 63;
  const int l16 = lane & 15, lg = lane >> 4;
  const int wid = tid >> 6, wr = wid >> 1, wc = wid & 1;
  const int m0 = blockIdx.x * 128, n0 = blockIdx.y * 128;
  f32x4 acc[4][4] = {};
  for (int k0 = 0; k0 < K; k0 += 32) {
#pragma unroll
    for (int hh = 0; hh < 2; ++hh) {
      int c = tid + hh * 256;           // 512 chunks of 16B per tile
      int row = c >> 2, col8 = (c & 3) << 3;
      __builtin_amdgcn_global_load_lds(
          (__attribute__((address_space(1))) void*)(A + (size_t)(m0 + row) * K + k0 + col8),
          (__attribute__((address_space(3))) void*)(Al + c * 8), 16, 0, 0);
      __builtin_amdgcn_global_load_lds(
          (__attribute__((address_space(1))) void*)(Bt + (size_t)(n0 + row) * K + k0 + col8),
          (__attribute__((address_space(3))) void*)(Bl + c * 8), 16, 0, 0);
    }
    __syncthreads();
    bfrag a[4], b[4];
#pragma unroll
    for (int mi = 0; mi < 4; ++mi)
      a[mi] = *reinterpret_cast<const bfrag*>(Al + (wr * 64 + mi * 16 + l16) * 32 + lg * 8);
#pragma unroll
    for (int ni = 0; ni < 4; ++ni)
      b[ni] = *reinterpret_cast<const bfrag*>(Bl + (wc * 64 + ni * 16 + l16) * 32 + lg * 8);
#pragma unroll
    for (int mi = 0; mi < 4; ++mi)
#pragma unroll
      for (int ni = 0; ni < 4; ++ni)
        acc[mi][ni] = __builtin_amdgcn_mfma_f32_16x16x32_bf16(a[mi], b[ni], acc[mi][ni], 0, 0, 0);
    __syncthreads();
  }
#pragma unroll
  for (int mi = 0; mi < 4; ++mi)
#pragma unroll
    for (int ni = 0; ni < 4; ++ni) {
      int col = n0 + wc * 64 + ni * 16 + l16;
      float bb = bias[col];
#pragma unroll
      for (int r = 0; r < 4; ++r) {
        int row = m0 + wr * 64 + mi * 16 + lg * 4 + r;
        float v = acc[mi][ni][r] + bb;
        if (STORE_BF16) ((u16*)Cout)[(size_t)row * N + col] = f2bf(v);
        else            ((float*)Cout)[(size_t)row * N + col] = v;
      }
    }
}

// ---------- flash attention ----------
// grid (S/64, NHEAD, B), 4 waves; wave = 16 query rows; KVBLK=64
__global__ __launch_bounds__(256) void k_attn(const u16* __restrict__ QKV,
                                              const u16* __restrict__ Vt,
                                              const int* __restrict__ amask,
                                              u16* __restrict__ ctx) {
  __shared__ __align__(16) u16 P[4][16][64];
  const int tid = threadIdx.x;
  const int lane = tid & 63;
  const int l16 = lane & 15, lg = lane >> 4;
  const int wid = tid >> 6;
  const int q0 = blockIdx.x * 64 + wid * 16;
  const int h = blockIdx.y, b = blockIdx.z;

  const u16* Qrow = QKV + (size_t)(b * SEQ + q0 + l16) * NQKV + h * 64;
  bfrag aq[2];
  aq[0] = *reinterpret_cast<const bfrag*>(Qrow + lg * 8);
  aq[1] = *reinterpret_cast<const bfrag*>(Qrow + 32 + lg * 8);
  const u16* Vb = Vt + (size_t)b * 64 * SEQ;

  float mrun[4], lrun[4];
#pragma unroll
  for (int r = 0; r < 4; ++r) { mrun[r] = -1e30f; lrun[r] = 0.f; }
  f32x4 accO[4] = {};

  for (int kv = 0; kv < SEQ; kv += 64) {
    float sc[4][4];
#pragma unroll
    for (int nt = 0; nt < 4; ++nt) {
      f32x4 s = {};
#pragma unroll
      for (int kb = 0; kb < 2; ++kb) {
        bfrag bk = *reinterpret_cast<const bfrag*>(
            QKV + (size_t)(b * SEQ + kv + nt * 16 + l16) * NQKV + HID + kb * 32 + lg * 8);
        s = __builtin_amdgcn_mfma_f32_16x16x32_bf16(aq[kb], bk, s, 0, 0, 0);
      }
      int mk = amask[b * SEQ + kv + nt * 16 + l16];
#pragma unroll
      for (int r = 0; r < 4; ++r)
        sc[nt][r] = mk ? s[r] * 0.125f : -1e30f;
    }
    // row stats: rows live at lg*4+r, cols spread over l16 -> reduce over 16-lane group
    float tmax[4];
#pragma unroll
    for (int r = 0; r < 4; ++r)
      tmax[r] = fmaxf(fmaxf(sc[0][r], sc[1][r]), fmaxf(sc[2][r], sc[3][r]));
#pragma unroll
    for (int off = 1; off <= 8; off <<= 1)
#pragma unroll
      for (int r = 0; r < 4; ++r)
        tmax[r] = fmaxf(tmax[r], __shfl_xor(tmax[r], off));

    float mnew[4], alpha[4], rsum[4], p[4][4];
#pragma unroll
    for (int r = 0; r < 4; ++r) {
      mnew[r] = fmaxf(mrun[r], tmax[r]);
      alpha[r] = __expf(mrun[r] - mnew[r]);
    }
#pragma unroll
    for (int nt = 0; nt < 4; ++nt)
#pragma unroll
      for (int r = 0; r < 4; ++r)
        p[nt][r] = __expf(sc[nt][r] - mnew[r]);
#pragma unroll
    for (int r = 0; r < 4; ++r)
      rsum[r] = p[0][r] + p[1][r] + p[2][r] + p[3][r];
#pragma unroll
    for (int off = 1; off <= 8; off <<= 1)
#pragma unroll
      for (int r = 0; r < 4; ++r)
        rsum[r] += __shfl_xor(rsum[r], off);
#pragma unroll
    for (int r = 0; r < 4; ++r) {
      lrun[r] = lrun[r] * alpha[r] + rsum[r];
      mrun[r] = mnew[r];
    }
#pragma unroll
    for (int nt = 0; nt < 4; ++nt)
#pragma unroll
      for (int r = 0; r < 4; ++r)
        accO[nt][r] *= alpha[r];

    __syncthreads();  // previous-iter P reads done (conservative)
#pragma unroll
    for (int nt = 0; nt < 4; ++nt)
#pragma unroll
      for (int r = 0; r < 4; ++r)
        P[wid][lg * 4 + r][nt * 16 + l16] = f2bf(p[nt][r]);
    __syncthreads();  // P visible

    bfrag ap[2];
    ap[0] = *reinterpret_cast<const bfrag*>(&P[wid][l16][lg * 8]);
    ap[1] = *reinterpret_cast<const bfrag*>(&P[wid][l16][32 + lg * 8]);
#pragma unroll
    for (int nt = 0; nt < 4; ++nt)
#pragma unroll
      for (int kb = 0; kb < 2; ++kb) {
        bfrag bv = *reinterpret_cast<const bfrag*>(
            Vb + (size_t)(nt * 16 + l16) * SEQ + kv + kb * 32 + lg * 8);
        accO[nt] = __builtin_amdgcn_mfma_f32_16x16x32_bf16(ap[kb], bv, accO[nt], 0, 0, 0);
      }
  }

  float invl[4];
#pragma unroll
  for (int r = 0; r < 4; ++r) invl[r] = 1.0f / lrun[r];
#pragma unroll
  for (int nt = 0; nt < 4; ++nt)
#pragma unroll
    for (int r = 0; r < 4; ++r)
      ctx[(size_t)(b * SEQ + q0 + lg * 4 + r) * HID + h * 64 + nt * 16 + l16] =
          f2bf(accO[nt][r] * invl[r]);
}

extern "C" void kernel_launch(void* const* d_in, const int* in_sizes, int n_in,
                              void* d_out, int out_size, void* d_ws, size_t ws_size,
                              hipStream_t stream) {
  const float* x  = (const float*)d_in[0];
  const int* am   = (const int*)d_in[1];
  const float* Wq = (const float*)d_in[2];
  const float* bq = (const float*)d_in[3];
  const float* Wk = (const float*)d_in[4];
  const float* bk = (const float*)d_in[5];
  const float* Wv = (const float*)d_in[6];
  const float* bv = (const float*)d_in[7];
  const float* Wo = (const float*)d_in[8];
  const float* bo = (const float*)d_in[9];

  char* ws = (char*)d_ws;
  u16*  Xb     = (u16*)(ws + 0);          //  8.00 MB  [4096][1024]
  u16*  Wt_qkv = (u16*)(ws + 8388608);    //  2.25 MB  [1152][1024]
  u16*  Wt_o   = (u16*)(ws + 10747904);   //  2.00 MB  [1024][1024]
  float* bqkv  = (float*)(ws + 12845056); //  4.5 KB
  u16*  QKV    = (u16*)(ws + 12849664);   //  9.00 MB  [4096][1152]
  u16*  Vt     = (u16*)(ws + 22286848);   //  0.50 MB  [2][64][2048]
  u16*  ctx    = (u16*)(ws + 22811136);   //  8.00 MB  [4096][1024]

  k_cvt_x<<<4096, 256, 0, stream>>>(x, Xb);
  k_cvt_wqkv<<<4608, 256, 0, stream>>>(Wq, Wk, Wv, Wt_qkv);
  k_cvt_wo<<<4096, 256, 0, stream>>>(Wo, Wt_o);
  k_bias<<<5, 256, 0, stream>>>(bq, bk, bv, bqkv);

  dim3 g1(32, 9);
  k_gemm<1><<<g1, 256, 0, stream>>>(Xb, Wt_qkv, bqkv, (void*)QKV, MROWS, NQKV, HID);

  k_vt<<<1024, 256, 0, stream>>>(QKV, Vt);

  dim3 g2(SEQ / 64, NHEAD, 2);
  k_attn<<<g2, 256, 0, stream>>>(QKV, Vt, am, ctx);

  dim3 g3(32, 8);
  k_gemm<0><<<g3, 256, 0, stream>>>(ctx, Wt_o, bo, d_out, MROWS, HID, HID);
}

// Round 2
// 294.669 us; speedup vs baseline: 1.6987x; 1.6987x over previous
//
#include <hip/hip_runtime.h>

#define SEQ   2048
#define NHEAD 16
#define HD    64
#define HID   1024
#define NQKV  1152
#define MROWS 4096  // B*S

typedef unsigned short u16;
typedef __attribute__((ext_vector_type(8))) __bf16 bfrag;
typedef __attribute__((ext_vector_type(4))) float f32x4;
typedef __attribute__((ext_vector_type(4))) short s16x4;

__device__ __forceinline__ u16 f2bf(float f) {
  unsigned u = __float_as_uint(f);
  u += 0x7fffu + ((u >> 16) & 1u);
  return (u16)(u >> 16);
}

// ---------- converts ----------
__global__ void k_cvt_x(const float* __restrict__ x, u16* __restrict__ o) {
  int i = (blockIdx.x * 256 + threadIdx.x) * 4;
  float4 v = *reinterpret_cast<const float4*>(x + i);
  s16x4 r;
  r.x = (short)f2bf(v.x); r.y = (short)f2bf(v.y);
  r.z = (short)f2bf(v.z); r.w = (short)f2bf(v.w);
  *reinterpret_cast<s16x4*>(o + i) = r;
}

// tiled transpose+convert: dst[nOff+n][k] = src[k][n]  (dst row stride 1024)
__global__ void k_tr(const float* __restrict__ src, int ld, u16* __restrict__ dst, int nOff) {
  __shared__ float T[64][65];
  const int t = threadIdx.x;
  const int k0 = blockIdx.x * 64, n0 = blockIdx.y * 64;
#pragma unroll
  for (int p = 0; p < 4; ++p) {
    int r = p * 16 + (t >> 4), c = (t & 15) * 4;
    float4 v = *reinterpret_cast<const float4*>(&src[(size_t)(k0 + r) * ld + n0 + c]);
    T[r][c] = v.x; T[r][c + 1] = v.y; T[r][c + 2] = v.z; T[r][c + 3] = v.w;
  }
  __syncthreads();
#pragma unroll
  for (int p = 0; p < 2; ++p) {
    int cc = t + p * 256;
    int n = cc >> 3, k8 = (cc & 7) * 8;
    union { float4 v; u16 u[8]; } o;
#pragma unroll
    for (int j = 0; j < 8; ++j) o.u[j] = f2bf(T[k8 + j][n]);
    *reinterpret_cast<float4*>(&dst[(size_t)(nOff + n0 + n) * 1024 + k0 + k8]) = o.v;
  }
}

__global__ void k_bias(const float* __restrict__ bq, const float* __restrict__ bk,
                       const float* __restrict__ bv, float* __restrict__ bqkv) {
  int t = blockIdx.x * 256 + threadIdx.x;
  if (t >= NQKV) return;
  float v;
  if (t < 1024)      v = bq[t];
  else if (t < 1088) v = bk[t - 1024];
  else               v = bv[t - 1088];
  bqkv[t] = v;
}

// Vt[b][d][s] = V[b][s][d]  (V = QKV cols 1088..1151)
__global__ void k_vt(const u16* __restrict__ QKV, u16* __restrict__ Vt) {
  int t = blockIdx.x * 256 + threadIdx.x;  // t < 2*64*2048
  int s = t & 2047, d = (t >> 11) & 63, b = t >> 17;
  Vt[t] = QKV[(size_t)(b * SEQ + s) * NQKV + 1088 + d];
}

// ---------- GEMM: C[M][N] = A[M][K] * Bt[N][K]^T + bias ----------
template <int STORE_BF16>
__global__ __launch_bounds__(256) void k_gemm(const u16* __restrict__ A,
                                              const u16* __restrict__ Bt,
                                              const float* __restrict__ bias,
                                              void* __restrict__ Cout,
                                              int M, int N, int K) {
  __shared__ __align__(16) u16 Al[128 * 32];
  __shared__ __align__(16) u16 Bl[128 * 32];
  const int tid = threadIdx.x;
  const int lane = tid & 63;
  const int l16 = lane & 15, lg = lane >> 4;
  const int wid = tid >> 6, wr = wid >> 1, wc = wid & 1;
  const int m0 = blockIdx.x * 128, n0 = blockIdx.y * 128;
  f32x4 acc[4][4] = {};
  for (int k0 = 0; k0 < K; k0 += 32) {
#pragma unroll
    for (int hh = 0; hh < 2; ++hh) {
      int c = tid + hh * 256;           // 512 chunks of 16B per tile
      int row = c >> 2, col8 = (c & 3) << 3;
      __builtin_amdgcn_global_load_lds(
          (__attribute__((address_space(1))) void*)(A + (size_t)(m0 + row) * K + k0 + col8),
          (__attribute__((address_space(3))) void*)(Al + c * 8), 16, 0, 0);
      __builtin_amdgcn_global_load_lds(
          (__attribute__((address_space(1))) void*)(Bt + (size_t)(n0 + row) * K + k0 + col8),
          (__attribute__((address_space(3))) void*)(Bl + c * 8), 16, 0, 0);
    }
    __syncthreads();
    bfrag a[4], b[4];
#pragma unroll
    for (int mi = 0; mi < 4; ++mi)
      a[mi] = *reinterpret_cast<const bfrag*>(Al + (wr * 64 + mi * 16 + l16) * 32 + lg * 8);
#pragma unroll
    for (int ni = 0; ni < 4; ++ni)
      b[ni] = *reinterpret_cast<const bfrag*>(Bl + (wc * 64 + ni * 16 + l16) * 32 + lg * 8);
#pragma unroll
    for (int mi = 0; mi < 4; ++mi)
#pragma unroll
      for (int ni = 0; ni < 4; ++ni)
        acc[mi][ni] = __builtin_amdgcn_mfma_f32_16x16x32_bf16(a[mi], b[ni], acc[mi][ni], 0, 0, 0);
    __syncthreads();
  }
#pragma unroll
  for (int mi = 0; mi < 4; ++mi)
#pragma unroll
    for (int ni = 0; ni < 4; ++ni) {
      int col = n0 + wc * 64 + ni * 16 + l16;
      float bb = bias[col];
#pragma unroll
      for (int r = 0; r < 4; ++r) {
        int row = m0 + wr * 64 + mi * 16 + lg * 4 + r;
        float v = acc[mi][ni][r] + bb;
        if (STORE_BF16) ((u16*)Cout)[(size_t)row * N + col] = f2bf(v);
        else            ((float*)Cout)[(size_t)row * N + col] = v;
      }
    }
}

// ---------- flash attention v2 ----------
// grid (S/64, NHEAD, B), 4 waves; wave = 16 query rows; KVBLK=64
// Swapped QK^T: scores rows = kv (lg*4+r), cols = q (l16).
// K staged in LDS (dbuf, XOR-swizzled); V prefetched to regs; mask bias in LDS.
__global__ __launch_bounds__(256, 4) void k_attn(const u16* __restrict__ QKV,
                                                 const u16* __restrict__ Vt,
                                                 const int* __restrict__ amask,
                                                 u16* __restrict__ ctx) {
  __shared__ __align__(16) u16 Kl[2][64 * 64];   // 16 KB, chunk cb stored at cb^(row&7)
  __shared__ __align__(16) u16 Pl[4][16][72];    // 9 KB, wave-private P
  __shared__ float mb[SEQ];                      // 8 KB mask bias
  const int tid = threadIdx.x;
  const int lane = tid & 63, l16 = lane & 15, lg = lane >> 4, wid = tid >> 6;
  const int q0 = blockIdx.x * 64 + wid * 16;
  const int h = blockIdx.y, b = blockIdx.z;

  for (int s = tid; s < SEQ; s += 256)
    mb[s] = amask[b * SEQ + s] ? 0.0f : -1e30f;

  const u16* Qrow = QKV + (size_t)(b * SEQ + q0 + l16) * NQKV + h * 64;
  const bfrag aq0 = *reinterpret_cast<const bfrag*>(Qrow + lg * 8);
  const bfrag aq1 = *reinterpret_cast<const bfrag*>(Qrow + 32 + lg * 8);
  const u16* Vb = Vt + (size_t)b * 64 * SEQ;
  const u16* Kg = QKV + (size_t)b * SEQ * NQKV + HID;  // K rows, stride NQKV

  auto stage_k = [&](int buf, int kv) {
#pragma unroll
    for (int hh = 0; hh < 2; ++hh) {
      int c = tid + hh * 256;                 // 512 chunks of 16B
      int r = c >> 3, cb = (c & 7) ^ (r & 7); // linear LDS dest, inv-swizzled source
      __builtin_amdgcn_global_load_lds(
          (__attribute__((address_space(1))) void*)(Kg + (size_t)(kv + r) * NQKV + cb * 8),
          (__attribute__((address_space(3))) void*)(&Kl[buf][c * 8]), 16, 0, 0);
    }
  };

  stage_k(0, 0);
  __syncthreads();  // drains vmcnt -> K buf0 + mb visible

  float mrun = -1e30f, lrun = 0.0f;  // softmax state for q = l16
  f32x4 accO[4] = {};                // rows q = lg*4+r, cols d = nt*16+l16

  for (int it = 0; it < SEQ / 64; ++it) {
    const int kv = it * 64;
    const int cur = it & 1;
    if (it + 1 < SEQ / 64) stage_k(cur ^ 1, kv + 64);

    // V prefetch: B-frag rows d = nt*16+l16, k = kv + kb*32 + lg*8
    bfrag vf[4][2];
#pragma unroll
    for (int nt = 0; nt < 4; ++nt)
#pragma unroll
      for (int kb = 0; kb < 2; ++kb)
        vf[nt][kb] = *reinterpret_cast<const bfrag*>(
            Vb + (size_t)(nt * 16 + l16) * SEQ + kv + kb * 32 + lg * 8);

    // QK^T from LDS K (swizzled read)
    f32x4 s[4];
#pragma unroll
    for (int nt = 0; nt < 4; ++nt) {
      f32x4 z = {};
      {
        int row = nt * 16 + l16;
        int cb0 = (0 * 4 + lg) ^ (l16 & 7);
        int cb1 = (1 * 4 + lg) ^ (l16 & 7);
        bfrag ak0 = *reinterpret_cast<const bfrag*>(&Kl[cur][row * 64 + cb0 * 8]);
        bfrag ak1 = *reinterpret_cast<const bfrag*>(&Kl[cur][row * 64 + cb1 * 8]);
        z = __builtin_amdgcn_mfma_f32_16x16x32_bf16(ak0, aq0, z, 0, 0, 0);
        z = __builtin_amdgcn_mfma_f32_16x16x32_bf16(ak1, aq1, z, 0, 0, 0);
      }
      s[nt] = z;
    }
    // scale + mask bias (broadcast LDS reads)
#pragma unroll
    for (int nt = 0; nt < 4; ++nt) {
      f32x4 mbv = *reinterpret_cast<const f32x4*>(&mb[kv + nt * 16 + lg * 4]);
#pragma unroll
      for (int r = 0; r < 4; ++r)
        s[nt][r] = s[nt][r] * 0.125f + mbv[r];
    }
    // kv-reduction: 15 in-lane + 2 shfl steps
    float tmax = s[0][0];
#pragma unroll
    for (int nt = 0; nt < 4; ++nt)
#pragma unroll
      for (int r = 0; r < 4; ++r) tmax = fmaxf(tmax, s[nt][r]);
    tmax = fmaxf(tmax, __shfl_xor(tmax, 16));
    tmax = fmaxf(tmax, __shfl_xor(tmax, 32));
    float mnew = fmaxf(mrun, tmax);
    float alpha = __expf(mrun - mnew);
    mrun = mnew;
    float rsum = 0.0f;
#pragma unroll
    for (int nt = 0; nt < 4; ++nt)
#pragma unroll
      for (int r = 0; r < 4; ++r) {
        s[nt][r] = __expf(s[nt][r] - mnew);
        rsum += s[nt][r];
      }
    rsum += __shfl_xor(rsum, 16);
    rsum += __shfl_xor(rsum, 32);
    lrun = lrun * alpha + rsum;
    // redistribute alpha to accO row layout (q = lg*4+r)
    float ar[4];
#pragma unroll
    for (int r = 0; r < 4; ++r) ar[r] = __shfl(alpha, lg * 4 + r);
#pragma unroll
    for (int nt = 0; nt < 4; ++nt)
#pragma unroll
      for (int r = 0; r < 4; ++r) accO[nt][r] *= ar[r];
    // P -> LDS (wave-private, no barrier): row q=l16, col kv-local
#pragma unroll
    for (int nt = 0; nt < 4; ++nt)
#pragma unroll
      for (int r = 0; r < 4; ++r)
        Pl[wid][l16][nt * 16 + lg * 4 + r] = f2bf(s[nt][r]);
    bfrag ap0 = *reinterpret_cast<const bfrag*>(&Pl[wid][l16][lg * 8]);
    bfrag ap1 = *reinterpret_cast<const bfrag*>(&Pl[wid][l16][32 + lg * 8]);
#pragma unroll
    for (int nt = 0; nt < 4; ++nt) {
      accO[nt] = __builtin_amdgcn_mfma_f32_16x16x32_bf16(ap0, vf[nt][0], accO[nt], 0, 0, 0);
      accO[nt] = __builtin_amdgcn_mfma_f32_16x16x32_bf16(ap1, vf[nt][1], accO[nt], 0, 0, 0);
    }
    __syncthreads();  // K dbuf swap (also orders P across iters)
  }

  float linv = 1.0f / lrun;
  float lr[4];
#pragma unroll
  for (int r = 0; r < 4; ++r) lr[r] = __shfl(linv, lg * 4 + r);
#pragma unroll
  for (int nt = 0; nt < 4; ++nt)
#pragma unroll
    for (int r = 0; r < 4; ++r)
      ctx[(size_t)(b * SEQ + q0 + lg * 4 + r) * HID + h * 64 + nt * 16 + l16] =
          f2bf(accO[nt][r] * lr[r]);
}

extern "C" void kernel_launch(void* const* d_in, const int* in_sizes, int n_in,
                              void* d_out, int out_size, void* d_ws, size_t ws_size,
                              hipStream_t stream) {
  const float* x  = (const float*)d_in[0];
  const int* am   = (const int*)d_in[1];
  const float* Wq = (const float*)d_in[2];
  const float* bq = (const float*)d_in[3];
  const float* Wk = (const float*)d_in[4];
  const float* bk = (const float*)d_in[5];
  const float* Wv = (const float*)d_in[6];
  const float* bv = (const float*)d_in[7];
  const float* Wo = (const float*)d_in[8];
  const float* bo = (const float*)d_in[9];

  char* ws = (char*)d_ws;
  u16*  Xb     = (u16*)(ws + 0);          //  8.00 MB  [4096][1024]
  u16*  Wt_qkv = (u16*)(ws + 8388608);    //  2.25 MB  [1152][1024]
  u16*  Wt_o   = (u16*)(ws + 10747904);   //  2.00 MB  [1024][1024]
  float* bqkv  = (float*)(ws + 12845056); //  4.5 KB
  u16*  QKV    = (u16*)(ws + 12849664);   //  9.00 MB  [4096][1152]
  u16*  Vt     = (u16*)(ws + 22286848);   //  0.50 MB  [2][64][2048]
  u16*  ctx    = (u16*)(ws + 22811136);   //  8.00 MB  [4096][1024]

  k_cvt_x<<<4096, 256, 0, stream>>>(x, Xb);
  k_tr<<<dim3(16, 16), 256, 0, stream>>>(Wq, 1024, Wt_qkv, 0);
  k_tr<<<dim3(16, 1), 256, 0, stream>>>(Wk, 64, Wt_qkv, 1024);
  k_tr<<<dim3(16, 1), 256, 0, stream>>>(Wv, 64, Wt_qkv, 1088);
  k_tr<<<dim3(16, 16), 256, 0, stream>>>(Wo, 1024, Wt_o, 0);
  k_bias<<<5, 256, 0, stream>>>(bq, bk, bv, bqkv);

  dim3 g1(32, 9);
  k_gemm<1><<<g1, 256, 0, stream>>>(Xb, Wt_qkv, bqkv, (void*)QKV, MROWS, NQKV, HID);

  k_vt<<<1024, 256, 0, stream>>>(QKV, Vt);

  dim3 g2(SEQ / 64, NHEAD, 2);
  k_attn<<<g2, 256, 0, stream>>>(QKV, Vt, am, ctx);

  dim3 g3(32, 8);
  k_gemm<0><<<g3, 256, 0, stream>>>(ctx, Wt_o, bo, d_out, MROWS, HID, HID);
}

// Round 4
// 278.523 us; speedup vs baseline: 1.7971x; 1.0580x over previous
//
#include <hip/hip_runtime.h>

#define SEQ   2048
#define NHEAD 16
#define HD    64
#define HID   1024
#define NQKV  1152
#define MROWS 4096  // B*S

typedef unsigned short u16;
typedef unsigned int u32;
typedef __attribute__((ext_vector_type(8))) __bf16 bfrag;
typedef __attribute__((ext_vector_type(4))) float f32x4;
typedef __attribute__((ext_vector_type(4))) short s16x4;

__device__ __forceinline__ u16 f2bf(float f) {
  unsigned u = __float_as_uint(f);
  u += 0x7fffu + ((u >> 16) & 1u);
  return (u16)(u >> 16);
}

// ---------- converts ----------
__global__ void k_cvt_x(const float* __restrict__ x, u16* __restrict__ o) {
  int i = (blockIdx.x * 256 + threadIdx.x) * 4;
  float4 v = *reinterpret_cast<const float4*>(x + i);
  s16x4 r;
  r.x = (short)f2bf(v.x); r.y = (short)f2bf(v.y);
  r.z = (short)f2bf(v.z); r.w = (short)f2bf(v.w);
  *reinterpret_cast<s16x4*>(o + i) = r;
}

// tiled transpose+convert: dst[nOff+n][k] = src[k][n]  (dst row stride 1024)
__global__ void k_tr(const float* __restrict__ src, int ld, u16* __restrict__ dst, int nOff) {
  __shared__ float T[64][65];
  const int t = threadIdx.x;
  const int k0 = blockIdx.x * 64, n0 = blockIdx.y * 64;
#pragma unroll
  for (int p = 0; p < 4; ++p) {
    int r = p * 16 + (t >> 4), c = (t & 15) * 4;
    float4 v = *reinterpret_cast<const float4*>(&src[(size_t)(k0 + r) * ld + n0 + c]);
    T[r][c] = v.x; T[r][c + 1] = v.y; T[r][c + 2] = v.z; T[r][c + 3] = v.w;
  }
  __syncthreads();
#pragma unroll
  for (int p = 0; p < 2; ++p) {
    int cc = t + p * 256;
    int n = cc >> 3, k8 = (cc & 7) * 8;
    union { float4 v; u16 u[8]; } o;
#pragma unroll
    for (int j = 0; j < 8; ++j) o.u[j] = f2bf(T[k8 + j][n]);
    *reinterpret_cast<float4*>(&dst[(size_t)(nOff + n0 + n) * 1024 + k0 + k8]) = o.v;
  }
}

__global__ void k_bias(const float* __restrict__ bq, const float* __restrict__ bk,
                       const float* __restrict__ bv, float* __restrict__ bqkv) {
  int t = blockIdx.x * 256 + threadIdx.x;
  if (t >= NQKV) return;
  float v;
  if (t < 1024)      v = bq[t];
  else if (t < 1088) v = bk[t - 1024];
  else               v = bv[t - 1088];
  bqkv[t] = v;
}

__global__ void k_mb(const int* __restrict__ am, float* __restrict__ Mbias) {
  int t = blockIdx.x * 256 + threadIdx.x;
  if (t < 2 * SEQ) Mbias[t] = am[t] ? 0.0f : -1e30f;
}

// Vt[b][d][s] = V[b][s][d]  (V = QKV cols 1088..1151)
__global__ void k_vt(const u16* __restrict__ QKV, u16* __restrict__ Vt) {
  int t = blockIdx.x * 256 + threadIdx.x;  // t < 2*64*2048
  int s = t & 2047, d = (t >> 11) & 63, b = t >> 17;
  Vt[t] = QKV[(size_t)(b * SEQ + s) * NQKV + 1088 + d];
}

// ---------- GEMM v2: 128x64 tile, BK=64, XOR-swizzled LDS ----------
// C[M][N] = A[M][K] * Bt[N][K]^T + bias. 4 waves; wave wid owns rows
// [wid*32, wid*32+32). LDS chunk ch of row r stored at slot ch^(r&7)
// (linear LDS dest + inverse-swizzled global source, per rule 21).
template <int STORE_BF16>
__global__ __launch_bounds__(256) void k_gemm(const u16* __restrict__ A,
                                              const u16* __restrict__ Bt,
                                              const float* __restrict__ bias,
                                              void* __restrict__ Cout,
                                              int M, int N, int K) {
  __shared__ __align__(16) u16 Al[128 * 64];
  __shared__ __align__(16) u16 Bl[64 * 64];
  const int tid = threadIdx.x;
  const int lane = tid & 63, l16 = lane & 15, lg = lane >> 4;
  const int wid = tid >> 6;
  const int m0 = blockIdx.x * 128, n0 = blockIdx.y * 64;
  f32x4 acc[2][4] = {};
  for (int k0 = 0; k0 < K; k0 += 64) {
#pragma unroll
    for (int p = 0; p < 4; ++p) {
      int c = tid + p * 256;            // 1024 chunks of 16B (A tile)
      int r = c >> 3, sl = c & 7;
      __builtin_amdgcn_global_load_lds(
          (__attribute__((address_space(1))) void*)(A + (size_t)(m0 + r) * K + k0 + ((sl ^ (r & 7)) << 3)),
          (__attribute__((address_space(3))) void*)(Al + c * 8), 16, 0, 0);
    }
#pragma unroll
    for (int p = 0; p < 2; ++p) {
      int c = tid + p * 256;            // 512 chunks of 16B (B tile)
      int r = c >> 3, sl = c & 7;
      __builtin_amdgcn_global_load_lds(
          (__attribute__((address_space(1))) void*)(Bt + (size_t)(n0 + r) * K + k0 + ((sl ^ (r & 7)) << 3)),
          (__attribute__((address_space(3))) void*)(Bl + c * 8), 16, 0, 0);
    }
    __syncthreads();
#pragma unroll
    for (int kk = 0; kk < 2; ++kk) {
      bfrag a[2], b[4];
#pragma unroll
      for (int mi = 0; mi < 2; ++mi) {
        int row = wid * 32 + mi * 16 + l16;
        a[mi] = *reinterpret_cast<const bfrag*>(
            Al + row * 64 + ((((kk << 2) | lg) ^ (l16 & 7)) << 3));
      }
#pragma unroll
      for (int ni = 0; ni < 4; ++ni) {
        int row = ni * 16 + l16;
        b[ni] = *reinterpret_cast<const bfrag*>(
            Bl + row * 64 + ((((kk << 2) | lg) ^ (l16 & 7)) << 3));
      }
#pragma unroll
      for (int mi = 0; mi < 2; ++mi)
#pragma unroll
        for (int ni = 0; ni < 4; ++ni)
          acc[mi][ni] = __builtin_amdgcn_mfma_f32_16x16x32_bf16(a[mi], b[ni], acc[mi][ni], 0, 0, 0);
    }
    __syncthreads();
  }
#pragma unroll
  for (int mi = 0; mi < 2; ++mi)
#pragma unroll
    for (int ni = 0; ni < 4; ++ni) {
      int col = n0 + ni * 16 + l16;
      float bb = bias[col];
#pragma unroll
      for (int r = 0; r < 4; ++r) {
        int row = m0 + wid * 32 + mi * 16 + lg * 4 + r;
        float v = acc[mi][ni][r] + bb;
        if (STORE_BF16) ((u16*)Cout)[(size_t)row * N + col] = f2bf(v);
        else            ((float*)Cout)[(size_t)row * N + col] = v;
      }
    }
}

// ---------- flash attention (round-2 proven version; mask bias from global) ----------
// grid (S/64, NHEAD, B), 4 waves; wave = 16 query rows; KVBLK=64
// Swapped QK^T: scores rows = kv (lg*4+r), cols = q (l16).
// K staged in LDS (dbuf, XOR-swizzled); V prefetched to regs.
__global__ __launch_bounds__(256, 4) void k_attn(const u16* __restrict__ QKV,
                                                 const u16* __restrict__ Vt,
                                                 const float* __restrict__ Mbias,
                                                 u16* __restrict__ ctx) {
  __shared__ __align__(16) u16 Kl[2][64 * 64];   // 16 KB, chunk cb stored at cb^(row&7)
  __shared__ __align__(16) u16 Pl[4][16][72];    // 9 KB, wave-private P
  const int tid = threadIdx.x;
  const int lane = tid & 63, l16 = lane & 15, lg = lane >> 4, wid = tid >> 6;
  const int q0 = blockIdx.x * 64 + wid * 16;
  const int h = blockIdx.y, b = blockIdx.z;

  const u16* Qrow = QKV + (size_t)(b * SEQ + q0 + l16) * NQKV + h * 64;
  const bfrag aq0 = *reinterpret_cast<const bfrag*>(Qrow + lg * 8);
  const bfrag aq1 = *reinterpret_cast<const bfrag*>(Qrow + 32 + lg * 8);
  const u16* Vb = Vt + (size_t)b * 64 * SEQ;
  const u16* Kg = QKV + (size_t)b * SEQ * NQKV + HID;  // K rows, stride NQKV
  const float* mb = Mbias + b * SEQ;

  auto stage_k = [&](int buf, int kv) {
#pragma unroll
    for (int hh = 0; hh < 2; ++hh) {
      int c = tid + hh * 256;                 // 512 chunks of 16B
      int r = c >> 3, cb = (c & 7) ^ (r & 7); // linear LDS dest, inv-swizzled source
      __builtin_amdgcn_global_load_lds(
          (__attribute__((address_space(1))) void*)(Kg + (size_t)(kv + r) * NQKV + cb * 8),
          (__attribute__((address_space(3))) void*)(&Kl[buf][c * 8]), 16, 0, 0);
    }
  };

  stage_k(0, 0);
  __syncthreads();  // drains vmcnt -> K buf0 visible

  float mrun = -1e30f, lrun = 0.0f;  // softmax state for q = l16
  f32x4 accO[4] = {};                // rows q = lg*4+r, cols d = nt*16+l16

  for (int it = 0; it < SEQ / 64; ++it) {
    const int kv = it * 64;
    const int cur = it & 1;
    if (it + 1 < SEQ / 64) stage_k(cur ^ 1, kv + 64);

    // V prefetch: B-frag rows d = nt*16+l16, k = kv + kb*32 + lg*8
    bfrag vf[4][2];
#pragma unroll
    for (int nt = 0; nt < 4; ++nt)
#pragma unroll
      for (int kb = 0; kb < 2; ++kb)
        vf[nt][kb] = *reinterpret_cast<const bfrag*>(
            Vb + (size_t)(nt * 16 + l16) * SEQ + kv + kb * 32 + lg * 8);

    // QK^T from LDS K (swizzled read)
    f32x4 s[4];
#pragma unroll
    for (int nt = 0; nt < 4; ++nt) {
      f32x4 z = {};
      {
        int row = nt * 16 + l16;
        int cb0 = (0 * 4 + lg) ^ (l16 & 7);
        int cb1 = (1 * 4 + lg) ^ (l16 & 7);
        bfrag ak0 = *reinterpret_cast<const bfrag*>(&Kl[cur][row * 64 + cb0 * 8]);
        bfrag ak1 = *reinterpret_cast<const bfrag*>(&Kl[cur][row * 64 + cb1 * 8]);
        z = __builtin_amdgcn_mfma_f32_16x16x32_bf16(ak0, aq0, z, 0, 0, 0);
        z = __builtin_amdgcn_mfma_f32_16x16x32_bf16(ak1, aq1, z, 0, 0, 0);
      }
      s[nt] = z;
    }
    // scale + mask bias (L2-resident broadcast reads)
#pragma unroll
    for (int nt = 0; nt < 4; ++nt) {
      f32x4 mbv = *reinterpret_cast<const f32x4*>(&mb[kv + nt * 16 + lg * 4]);
#pragma unroll
      for (int r = 0; r < 4; ++r)
        s[nt][r] = s[nt][r] * 0.125f + mbv[r];
    }
    // kv-reduction: 15 in-lane + 2 shfl steps
    float tmax = s[0][0];
#pragma unroll
    for (int nt = 0; nt < 4; ++nt)
#pragma unroll
      for (int r = 0; r < 4; ++r) tmax = fmaxf(tmax, s[nt][r]);
    tmax = fmaxf(tmax, __shfl_xor(tmax, 16));
    tmax = fmaxf(tmax, __shfl_xor(tmax, 32));
    float mnew = fmaxf(mrun, tmax);
    float alpha = __expf(mrun - mnew);
    mrun = mnew;
    float rsum = 0.0f;
#pragma unroll
    for (int nt = 0; nt < 4; ++nt)
#pragma unroll
      for (int r = 0; r < 4; ++r) {
        s[nt][r] = __expf(s[nt][r] - mnew);
        rsum += s[nt][r];
      }
    rsum += __shfl_xor(rsum, 16);
    rsum += __shfl_xor(rsum, 32);
    lrun = lrun * alpha + rsum;
    // redistribute alpha to accO row layout (q = lg*4+r)
    float ar[4];
#pragma unroll
    for (int r = 0; r < 4; ++r) ar[r] = __shfl(alpha, lg * 4 + r);
#pragma unroll
    for (int nt = 0; nt < 4; ++nt)
#pragma unroll
      for (int r = 0; r < 4; ++r) accO[nt][r] *= ar[r];
    // P -> LDS (wave-private, no barrier): row q=l16, col kv-local
#pragma unroll
    for (int nt = 0; nt < 4; ++nt)
#pragma unroll
      for (int r = 0; r < 4; ++r)
        Pl[wid][l16][nt * 16 + lg * 4 + r] = f2bf(s[nt][r]);
    bfrag ap0 = *reinterpret_cast<const bfrag*>(&Pl[wid][l16][lg * 8]);
    bfrag ap1 = *reinterpret_cast<const bfrag*>(&Pl[wid][l16][32 + lg * 8]);
#pragma unroll
    for (int nt = 0; nt < 4; ++nt) {
      accO[nt] = __builtin_amdgcn_mfma_f32_16x16x32_bf16(ap0, vf[nt][0], accO[nt], 0, 0, 0);
      accO[nt] = __builtin_amdgcn_mfma_f32_16x16x32_bf16(ap1, vf[nt][1], accO[nt], 0, 0, 0);
    }
    __syncthreads();  // K dbuf swap (also orders P across iters)
  }

  float linv = 1.0f / lrun;
  float lr[4];
#pragma unroll
  for (int r = 0; r < 4; ++r) lr[r] = __shfl(linv, lg * 4 + r);
#pragma unroll
  for (int nt = 0; nt < 4; ++nt)
#pragma unroll
    for (int r = 0; r < 4; ++r)
      ctx[(size_t)(b * SEQ + q0 + lg * 4 + r) * HID + h * 64 + nt * 16 + l16] =
          f2bf(accO[nt][r] * lr[r]);
}

extern "C" void kernel_launch(void* const* d_in, const int* in_sizes, int n_in,
                              void* d_out, int out_size, void* d_ws, size_t ws_size,
                              hipStream_t stream) {
  const float* x  = (const float*)d_in[0];
  const int* am   = (const int*)d_in[1];
  const float* Wq = (const float*)d_in[2];
  const float* bq = (const float*)d_in[3];
  const float* Wk = (const float*)d_in[4];
  const float* bk = (const float*)d_in[5];
  const float* Wv = (const float*)d_in[6];
  const float* bv = (const float*)d_in[7];
  const float* Wo = (const float*)d_in[8];
  const float* bo = (const float*)d_in[9];

  char* ws = (char*)d_ws;
  u16*  Xb     = (u16*)(ws + 0);          //  8.00 MB  [4096][1024]
  u16*  Wt_qkv = (u16*)(ws + 8388608);    //  2.25 MB  [1152][1024]
  u16*  Wt_o   = (u16*)(ws + 10747904);   //  2.00 MB  [1024][1024]
  float* bqkv  = (float*)(ws + 12845056); //  4.5 KB
  float* Mbias = (float*)(ws + 12849664); // 16 KB    [2][2048]
  u16*  QKV    = (u16*)(ws + 12866048);   //  9.00 MB  [4096][1152]
  u16*  Vt     = (u16*)(ws + 22303232);   //  0.50 MB  [2][64][2048]
  u16*  ctx    = (u16*)(ws + 22827520);   //  8.00 MB  [4096][1024]

  k_cvt_x<<<4096, 256, 0, stream>>>(x, Xb);
  k_tr<<<dim3(16, 16), 256, 0, stream>>>(Wq, 1024, Wt_qkv, 0);
  k_tr<<<dim3(16, 1), 256, 0, stream>>>(Wk, 64, Wt_qkv, 1024);
  k_tr<<<dim3(16, 1), 256, 0, stream>>>(Wv, 64, Wt_qkv, 1088);
  k_tr<<<dim3(16, 16), 256, 0, stream>>>(Wo, 1024, Wt_o, 0);
  k_bias<<<5, 256, 0, stream>>>(bq, bk, bv, bqkv);
  k_mb<<<16, 256, 0, stream>>>(am, Mbias);

  dim3 g1(32, 18);
  k_gemm<1><<<g1, 256, 0, stream>>>(Xb, Wt_qkv, bqkv, (void*)QKV, MROWS, NQKV, HID);

  k_vt<<<1024, 256, 0, stream>>>(QKV, Vt);

  dim3 g2(SEQ / 64, NHEAD, 2);
  k_attn<<<g2, 256, 0, stream>>>(QKV, Vt, Mbias, ctx);

  dim3 g3(32, 16);
  k_gemm<0><<<g3, 256, 0, stream>>>(ctx, Wt_o, bo, d_out, MROWS, HID, HID);
}